// Round 6
// baseline (245.205 us; speedup 1.0000x reference)
//
#include <hip/hip_runtime.h>
#include <math.h>

#define B_ 2
#define DMODEL 128
#define DIN 256
#define DSTATE 16
#define DTR 8
#define OUTC 128
#define Lseq 4096
#define NC 512          // chunks per batch
#define LC 8            // timesteps per chunk

__device__ __forceinline__ float siluf(float x){ return x / (1.f + __expf(-x)); }

// dA[s] = e1^(s+1), s=0..15, via log-depth power ladder (15 muls, depth ~4).
__device__ __forceinline__ void build_dA(float e1, float* dAv){
    float e2 = e1*e1, e4 = e2*e2, e8 = e4*e4;
    dAv[0]=e1;         dAv[1]=e2;         dAv[2]=e2*e1;       dAv[3]=e4;
    dAv[4]=e4*e1;      dAv[5]=e4*e2;      dAv[6]=e4*dAv[2];   dAv[7]=e8;
    dAv[8]=e8*e1;      dAv[9]=e8*e2;      dAv[10]=e8*dAv[2];  dAv[11]=e8*e4;
    dAv[12]=e8*dAv[4]; dAv[13]=e8*dAv[5]; dAv[14]=e8*dAv[6];  dAv[15]=e8*e8;
}

__device__ __forceinline__ float softplusf(float a){
    return (a > 20.f) ? a : __logf(1.f + __expf(a));
}

// ---------------- Kernel AB (fused): in_proj + conv + silu + x_proj + dt_proj + scan pass 1 --------------
// Round-4 fix: occupancy was GRID-limited (2 blocks/CU). Keep the verified 256-thread round-2 structure
// (thread t computes BOTH xin col t and z col t: 35 FMA/k of ILP) but halve the chunk: LC=8 -> 1024 blocks
// -> 4 blocks/CU = 16 waves/CU (the VGPR=100 cap). Halo cost: +3 of 8 l on xin half (~8.5% total FLOPs).
__global__ __launch_bounds__(256) void k_inconv_scan1(const float* __restrict__ x1,
        const float* __restrict__ Win,
        const float* __restrict__ convw, const float* __restrict__ convb,
        const float* __restrict__ Wx, const float* __restrict__ Wdt,
        const float* __restrict__ bdt, const float* __restrict__ Alog,
        float* __restrict__ zs, float* __restrict__ xc, float* __restrict__ dt,
        float* __restrict__ Bm, float* __restrict__ Cm, float2* __restrict__ PSw){
    __shared__ float xt[128*16];       // x tile [c][j], j=0..15 -> l = l0-8+j (float4-aligned linear copy)
    __shared__ float xcs[8*257];       // conv output [l][d]
    __shared__ float xdbl[8*40];       // x_proj output [l][40]
    int blk = blockIdx.x;              // 1024 = b x 512 chunks
    int b  = blk >> 9;
    int cb = blk & 511;
    int l0 = cb << 3;
    int t  = threadIdx.x;

    // ---- phase 0: stage x tile (16 timesteps l0-8..l0+7, zero-fill l<0) ----
    const float* xb = x1 + (size_t)b * DMODEL * Lseq;
    {
        float4 z4 = make_float4(0.f,0.f,0.f,0.f);
        #pragma unroll
        for (int e = t; e < 128*4; e += 256){
            int c = e >> 2, i = e & 3;
            int l = l0 - 8 + i*4;
            float4 v = (l >= 0) ? *(const float4*)&xb[(size_t)c*Lseq + l] : z4;
            *(float4*)&xt[e*4] = v;    // e*4 == c*16 + i*4
        }
    }
    __syncthreads();

    // ---- phase 1: in_proj GEMM. thread t -> xin col t (11 l incl 3-l halo) + z col t (8 l) ----
    float acc0[11], acc1[8];
    #pragma unroll
    for (int p=0;p<11;++p) acc0[p]=0.f;
    #pragma unroll
    for (int p=0;p<8;++p)  acc1[p]=0.f;
    #pragma unroll 4
    for (int k=0;k<128;++k){
        float w0 = Win[k*512 + t];
        float w1 = Win[k*512 + t + 256];
        const float4* xp = (const float4*)&xt[k*16];
        float4 x1_ = xp[1], x2_ = xp[2], x3_ = xp[3];   // j = 4..15
        // acc0[p] : l = l0-3+p -> j = p+5 (j=5..15)
        acc0[0] =fmaf(x1_.y, w0, acc0[0]);  acc0[1] =fmaf(x1_.z, w0, acc0[1]);
        acc0[2] =fmaf(x1_.w, w0, acc0[2]);  acc0[3] =fmaf(x2_.x, w0, acc0[3]);
        acc0[4] =fmaf(x2_.y, w0, acc0[4]);  acc0[5] =fmaf(x2_.z, w0, acc0[5]);
        acc0[6] =fmaf(x2_.w, w0, acc0[6]);  acc0[7] =fmaf(x3_.x, w0, acc0[7]);
        acc0[8] =fmaf(x3_.y, w0, acc0[8]);  acc0[9] =fmaf(x3_.z, w0, acc0[9]);
        acc0[10]=fmaf(x3_.w, w0, acc0[10]);
        // acc1[p] : l = l0+p -> j = p+8 (j=8..15)
        acc1[0] =fmaf(x2_.x, w1, acc1[0]);  acc1[1] =fmaf(x2_.y, w1, acc1[1]);
        acc1[2] =fmaf(x2_.z, w1, acc1[2]);  acc1[3] =fmaf(x2_.w, w1, acc1[3]);
        acc1[4] =fmaf(x3_.x, w1, acc1[4]);  acc1[5] =fmaf(x3_.y, w1, acc1[5]);
        acc1[6] =fmaf(x3_.z, w1, acc1[6]);  acc1[7] =fmaf(x3_.w, w1, acc1[7]);
    }
    // z gate -> zs
    {
        float* zp = zs + ((size_t)(b*Lseq + l0))*DIN + t;
        #pragma unroll
        for (int p=0;p<8;++p) zp[p*DIN] = siluf(acc1[p]);
    }
    // ---- phase 2: causal depthwise conv + silu straight from acc0 registers ----
    {
        float cw0 = convw[t*4+0], cw1 = convw[t*4+1], cw2 = convw[t*4+2], cw3 = convw[t*4+3];
        float bb = convb[t];
        float* xcg = xc + ((size_t)(b*Lseq + l0))*DIN + t;
        #pragma unroll
        for (int l = 0; l < LC; ++l){
            float acc = bb;
            acc = fmaf(acc0[l],   cw0, acc);
            acc = fmaf(acc0[l+1], cw1, acc);
            acc = fmaf(acc0[l+2], cw2, acc);
            acc = fmaf(acc0[l+3], cw3, acc);
            float v = siluf(acc);
            xcs[l*257 + t] = v;
            xcg[l*DIN] = v;
        }
    }
    __syncthreads();

    // ---- phase 3: x_proj. BC cols: 256 threads = 8 rows x 32 cols. dt cols: t<64 tail (8 rows x 8). ----
    {
        int row = t >> 5, col = t & 31;
        float a = 0.f;
        const float* xrow = xcs + row*257;
        const float* wb = Wx + 8 + col;
        #pragma unroll 8
        for (int d = 0; d < 256; ++d)
            a = fmaf(xrow[d], wb[d*40], a);
        xdbl[row*40 + 8 + col] = a;
    }
    if (t < 64){
        int row = t >> 3, r = t & 7;
        float a = 0.f;
        const float* xrow = xcs + row*257;
        const float* wb = Wx + r;
        #pragma unroll 8
        for (int d = 0; d < 256; ++d)
            a = fmaf(xrow[d], wb[d*40], a);
        xdbl[row*40 + r] = a;
    }
    __syncthreads();

    // ---- phase 4: dt_proj + softplus + fused scan pass 1 ----
    {
        float wd[DTR];
        #pragma unroll
        for (int r=0;r<DTR;++r) wd[r] = Wdt[r*DIN + t];
        float bv = bdt[t];
        float Av[16];
        {
            const float4* Ap = (const float4*)(Alog + t*DSTATE);
            #pragma unroll
            for (int q=0;q<4;++q){
                float4 a = Ap[q];
                Av[q*4]   = -__expf(a.x);
                Av[q*4+1] = -__expf(a.y);
                Av[q*4+2] = -__expf(a.z);
                Av[q*4+3] = -__expf(a.w);
            }
        }
        bool fastA = true;
        #pragma unroll
        for (int i=1;i<16;++i)
            fastA = fastA && (fabsf(Av[i] - (float)(i+1)*Av[0]) <= 1e-6f*fabsf(Av[i]));
        float P[16], S[16];
        #pragma unroll
        for (int s=0;s<16;++s){ P[s]=1.f; S[s]=0.f; }
        float* dtg = dt + ((size_t)(b*Lseq + l0))*DIN + t;
        #pragma unroll
        for (int l=0;l<LC;++l){
            float a = bv;
            #pragma unroll
            for (int r=0;r<DTR;++r) a = fmaf(xdbl[l*40 + r], wd[r], a);
            float dtv = softplusf(a);
            dtg[l*DIN] = dtv;
            float xcv = xcs[l*257 + t];
            float dx  = dtv*xcv;
            const float4* Bv = (const float4*)&xdbl[l*40 + DTR];
            float4 B0 = Bv[0], B1 = Bv[1], B2 = Bv[2], B3 = Bv[3];
            float dAv[16];
            if (fastA){
                build_dA(__expf(dtv*Av[0]), dAv);
            } else {
                #pragma unroll
                for (int i=0;i<16;++i) dAv[i] = __expf(dtv*Av[i]);
            }
            #define ST1(i, bval) { P[i] *= dAv[i]; S[i] = fmaf(dAv[i], S[i], dx*(bval)); }
            ST1(0,B0.x) ST1(1,B0.y) ST1(2,B0.z) ST1(3,B0.w)
            ST1(4,B1.x) ST1(5,B1.y) ST1(6,B1.z) ST1(7,B1.w)
            ST1(8,B2.x) ST1(9,B2.y) ST1(10,B2.z) ST1(11,B2.w)
            ST1(12,B3.x) ST1(13,B3.y) ST1(14,B3.z) ST1(15,B3.w)
            #undef ST1
        }
        float2* ps = PSw + ((size_t)(b*NC + cb))*4096 + t*DSTATE;
        #pragma unroll
        for (int s=0;s<16;++s) ps[s] = make_float2(P[s], S[s]);
    }
    // ---- B/C extraction (8 l x 32 cols = 256 elements, one per thread) ----
    {
        int l = t >> 5, q = t & 31;
        float v = xdbl[l*40 + DTR + q];
        size_t g = ((size_t)(b*Lseq + l0 + l))*DSTATE;
        if (q < DSTATE) Bm[g + q] = v;
        else            Cm[g + (q - DSTATE)] = v;
    }
}

// ---------------- Kernel C: pass 2, hierarchical chunk combine; entry states written IN-PLACE into PSw ---
// 512 blocks = b x 256 channel-groups of 16. cg = t>>4 handles 32 chunks; pass A composes (no reg arrays),
// LDS scan stitches 16 groups, pass B re-reads PSw (L2/L3-hot) and overwrites each entry with (H_entry, 0).
__global__ __launch_bounds__(256) void k_scan2(float2* __restrict__ PSw){
    __shared__ float2 gps[16][16];
    __shared__ float  ge [16][16];
    int blk = blockIdx.x;               // 512 = b x 256 channel-groups of 16
    int b  = blk >> 8;
    int r0 = (blk & 255) * 16;
    int t  = threadIdx.x;
    int rr = t & 15;                    // channel within group
    int cg = t >> 4;                    // chunk-group 0..15 (32 chunks each)
    size_t base = ((size_t)(b*NC + cg*32))*4096 + r0 + rr;
    float Pa = 1.f, Sa = 0.f;
    #pragma unroll 8
    for (int i=0;i<32;++i){
        float2 ps = PSw[base + (size_t)i*4096];
        Pa = ps.x * Pa;
        Sa = fmaf(ps.x, Sa, ps.y);
    }
    gps[cg][rr] = make_float2(Pa, Sa);
    __syncthreads();
    if (t < 16){
        float H = 0.f;
        #pragma unroll
        for (int g=0; g<16; ++g){
            float2 ps = gps[g][t];
            ge[g][t] = H;
            H = fmaf(ps.x, H, ps.y);
        }
    }
    __syncthreads();
    float H = ge[cg][rr];
    #pragma unroll 8
    for (int i=0;i<32;++i){
        size_t idx = base + (size_t)i*4096;
        float2 ps = PSw[idx];
        PSw[idx] = make_float2(H, 0.f);     // entry state for this chunk (read-then-overwrite, same thread)
        H = fmaf(ps.x, H, ps.y);
    }
}

// ---------------- Kernel D: fused scan pass 3 + out_proj + LayerNorm + NCHW store -----------------------
// 1024 blocks (b x 512 chunks of 8 l), 256 threads (reverted to the verified 256-thread structure).
__global__ __launch_bounds__(256) void k_scan3out(const float* __restrict__ dt,
        const float* __restrict__ xc, const float* __restrict__ zs,
        const float* __restrict__ Bm, const float* __restrict__ Cm,
        const float* __restrict__ Alog, const float* __restrict__ Dv,
        const float2* __restrict__ PSw,
        const float* __restrict__ Wout, const float* __restrict__ lng,
        const float* __restrict__ lnb, float* __restrict__ out){
    __shared__ float ysm[256*9];       // [d][l] stride 9
    __shared__ float os[128*12];       // [c][l] stride 12 (16B-aligned float4 rows)
    __shared__ float Bs[LC*DSTATE];    // 128
    __shared__ float Cs[LC*DSTATE];
    int blk = blockIdx.x;
    int b = blk >> 9, c = blk & 511;
    int l0 = c * LC;
    int t = threadIdx.x;               // = d in scan phase
    size_t gb = (size_t)(b*Lseq + l0);
    if (t < 128)      Bs[t]       = Bm[gb*DSTATE + t];
    else              Cs[t - 128] = Cm[gb*DSTATE + (t - 128)];

    float Av[16];
    {
        const float4* Ap = (const float4*)(Alog + t*DSTATE);
        #pragma unroll
        for (int q=0;q<4;++q){
            float4 a = Ap[q];
            Av[q*4]   = -__expf(a.x);
            Av[q*4+1] = -__expf(a.y);
            Av[q*4+2] = -__expf(a.z);
            Av[q*4+3] = -__expf(a.w);
        }
    }
    bool fastA = true;
    #pragma unroll
    for (int i=1;i<16;++i)
        fastA = fastA && (fabsf(Av[i] - (float)(i+1)*Av[0]) <= 1e-6f*fabsf(Av[i]));
    float h[16];
    {   // entry states live in PSw[...].x (written in-place by k_scan2)
        const float4* Ip = (const float4*)(PSw + ((size_t)(b*NC + c))*4096 + t*DSTATE);
        #pragma unroll
        for (int q=0;q<8;++q){
            float4 v = Ip[q];          // = {P2q.x(H), P2q.y(0), P2q+1.x(H), P2q+1.y(0)}
            h[q*2]   = v.x;
            h[q*2+1] = v.z;
        }
    }
    float Dd = Dv[t];
    float dtv[LC], xcv[LC], zvv[LC];
    {
        const float* dtp = dt + gb*DIN + t;
        const float* xcp = xc + gb*DIN + t;
        const float* zsp = zs + gb*DIN + t;
        #pragma unroll
        for (int l=0;l<LC;++l){
            dtv[l] = dtp[l*DIN];
            xcv[l] = xcp[l*DIN];
            zvv[l] = zsp[l*DIN];
        }
    }
    __syncthreads();
    #pragma unroll
    for (int l=0;l<LC;++l){
        float dtl = dtv[l];
        float dx  = dtl*xcv[l];
        const float4* Bv = (const float4*)&Bs[l*DSTATE];
        const float4* Cv = (const float4*)&Cs[l*DSTATE];
        float4 B0 = Bv[0], B1 = Bv[1], B2 = Bv[2], B3 = Bv[3];
        float4 C0 = Cv[0], C1 = Cv[1], C2 = Cv[2], C3 = Cv[3];
        float dAv[16];
        if (fastA){
            build_dA(__expf(dtl*Av[0]), dAv);
        } else {
            #pragma unroll
            for (int i=0;i<16;++i) dAv[i] = __expf(dtl*Av[i]);
        }
        float y = 0.f;
        #define ST3(i, bval, cval) { h[i] = fmaf(dAv[i], h[i], dx*(bval)); y = fmaf(h[i], (cval), y); }
        ST3(0,B0.x,C0.x) ST3(1,B0.y,C0.y) ST3(2,B0.z,C0.z) ST3(3,B0.w,C0.w)
        ST3(4,B1.x,C1.x) ST3(5,B1.y,C1.y) ST3(6,B1.z,C1.z) ST3(7,B1.w,C1.w)
        ST3(8,B2.x,C2.x) ST3(9,B2.y,C2.y) ST3(10,B2.z,C2.z) ST3(11,B2.w,C2.w)
        ST3(12,B3.x,C3.x) ST3(13,B3.y,C3.y) ST3(14,B3.z,C3.z) ST3(15,B3.w,C3.w)
        #undef ST3
        ysm[t*9 + l] = (y + Dd*xcv[l])*zvv[l];
    }
    __syncthreads();
    // ---- out_proj: 256 threads, 1 l x 4 c each. lr = t>>5 (0..7), cg = t&31 -> c0 = cg*4.
    int lr = t >> 5, cg = t & 31;
    int c0 = cg*4;
    float a0=0.f, a1=0.f, a2=0.f, a3=0.f;
    #pragma unroll 4
    for (int k=0;k<DIN;++k){
        float yv = ysm[k*9 + lr];
        float4 wv = *(const float4*)&Wout[k*OUTC + c0];
        a0 = fmaf(yv, wv.x, a0);
        a1 = fmaf(yv, wv.y, a1);
        a2 = fmaf(yv, wv.z, a2);
        a3 = fmaf(yv, wv.w, a3);
    }
    // LayerNorm over c: reduce across the 32 lanes sharing this l (xor<=16 stays in half-wave)
    {
        float4 gm = *(const float4*)&lng[c0];
        float4 bt = *(const float4*)&lnb[c0];
        float rs = a0+a1+a2+a3;
        #pragma unroll
        for (int m=16;m>0;m>>=1) rs += __shfl_xor(rs, m, 64);
        float mu = rs * (1.f/128.f);
        float d0 = a0-mu, d1 = a1-mu, d2 = a2-mu, d3 = a3-mu;
        float sq = d0*d0+d1*d1+d2*d2+d3*d3;
        #pragma unroll
        for (int m=16;m>0;m>>=1) sq += __shfl_xor(sq, m, 64);
        float rstd = rsqrtf(sq * (1.f/128.f) + 1e-5f);
        os[(c0+0)*12 + lr] = d0*rstd*gm.x + bt.x;
        os[(c0+1)*12 + lr] = d1*rstd*gm.y + bt.y;
        os[(c0+2)*12 + lr] = d2*rstd*gm.z + bt.z;
        os[(c0+3)*12 + lr] = d3*rstd*gm.w + bt.w;
    }
    __syncthreads();
    // store: cc = t>>1 (0..127), sel = t&1 -> 4 consecutive l = one float4 per lane
    {
        int cc = t >> 1, sel = t & 1;
        float4 v = *(const float4*)&os[cc*12 + sel*4];
        float* op = out + ((size_t)(b*OUTC + cc))*Lseq + l0 + sel*4;
        *(float4*)op = v;
    }
}

extern "C" void kernel_launch(void* const* d_in, const int* in_sizes, int n_in,
                              void* d_out, int out_size, void* d_ws, size_t ws_size,
                              hipStream_t stream) {
    const float* x1    = (const float*)d_in[0];
    const float* Win   = (const float*)d_in[1];
    const float* convw = (const float*)d_in[2];
    const float* convb = (const float*)d_in[3];
    const float* Wx    = (const float*)d_in[4];
    const float* Wdt   = (const float*)d_in[5];
    const float* bdt   = (const float*)d_in[6];
    const float* Alog  = (const float*)d_in[7];
    const float* Dv    = (const float*)d_in[8];
    const float* Wout  = (const float*)d_in[9];
    const float* lng   = (const float*)d_in[10];
    const float* lnb   = (const float*)d_in[11];
    float* out = (float*)d_out;

    float* ws  = (float*)d_ws;
    float* zs  = ws;                        // 2,097,152 floats
    float* xc  = zs  + 2097152;             // 2,097,152
    float* dt  = xc  + 2097152;             // 2,097,152
    float* Bm  = dt  + 2097152;             //   131,072
    float* Cm  = Bm  + 131072;              //   131,072
    float2* PSw = (float2*)(Cm + 131072);   // 4,194,304 float2 = 8,388,608 floats (~59.8 MB total)

    k_inconv_scan1<<<1024, 256, 0, stream>>>(x1, Win, convw, convb, Wx, Wdt, bdt, Alog,
                                             zs, xc, dt, Bm, Cm, PSw);
    k_scan2       <<<512,  256, 0, stream>>>(PSw);
    k_scan3out    <<<1024, 256, 0, stream>>>(dt, xc, zs, Bm, Cm, Alog, Dv, PSw,
                                             Wout, lng, lnb, out);
}

// Round 7
// 186.970 us; speedup vs baseline: 1.3115x; 1.3115x over previous
//
#include <hip/hip_runtime.h>
#include <math.h>

#define B_ 2
#define DMODEL 128
#define DIN 256
#define DSTATE 16
#define DTR 8
#define OUTC 128
#define Lseq 4096
#define NC 256          // chunks per batch
#define LC 16           // timesteps per chunk

__device__ __forceinline__ float siluf(float x){ return x / (1.f + __expf(-x)); }

// dA[s] = e1^(s+1), s=0..15, via log-depth power ladder (15 muls, depth ~4).
__device__ __forceinline__ void build_dA(float e1, float* dAv){
    float e2 = e1*e1, e4 = e2*e2, e8 = e4*e4;
    dAv[0]=e1;         dAv[1]=e2;         dAv[2]=e2*e1;       dAv[3]=e4;
    dAv[4]=e4*e1;      dAv[5]=e4*e2;      dAv[6]=e4*dAv[2];   dAv[7]=e8;
    dAv[8]=e8*e1;      dAv[9]=e8*e2;      dAv[10]=e8*dAv[2];  dAv[11]=e8*e4;
    dAv[12]=e8*dAv[4]; dAv[13]=e8*dAv[5]; dAv[14]=e8*dAv[6];  dAv[15]=e8*e8;
}

__device__ __forceinline__ float softplusf(float a){
    return (a > 20.f) ? a : __logf(1.f + __expf(a));
}

// ---------------- Kernel AB (fused): in_proj + conv + silu + x_proj + dt_proj + scan pass 1 --------------
// ROUND-2 measured structure (63 us, best) + 8-deep register-pipelined Win prefetch in the GEMM k-loop.
// Thread t owns xin col t (19 l incl 3-l halo, conv from registers) and z col t. 512 blocks x 256 thr.
__global__ __launch_bounds__(256) void k_inconv_scan1(const float* __restrict__ x1,
        const float* __restrict__ Win,
        const float* __restrict__ convw, const float* __restrict__ convb,
        const float* __restrict__ Wx, const float* __restrict__ Wdt,
        const float* __restrict__ bdt, const float* __restrict__ Alog,
        float* __restrict__ zs, float* __restrict__ xc, float* __restrict__ dt,
        float* __restrict__ Bm, float* __restrict__ Cm, float2* __restrict__ PSw){
    __shared__ float xt[128*20];       // x tile [c][p], p=0..18 -> l = l0-3+p (pad stride 20)
    __shared__ float xcs[16*257];      // conv output [l][d]
    __shared__ float xdbl[16*40];      // x_proj output [l][40]
    int blk = blockIdx.x;              // 512 = b x 256 chunks
    int b  = blk >> 8;
    int cb = blk & 255;
    int l0 = cb << 4;
    int t  = threadIdx.x;

    // ---- phase 0: stage x tile (19 timesteps incl. 3-l causal halo, zeros at l<0) ----
    const float* xb = x1 + (size_t)b * DMODEL * Lseq;
    for (int e = t; e < 128*19; e += 256){
        int c = e / 19, p = e - c*19;
        int l = l0 - 3 + p;
        xt[c*20 + p] = (l >= 0) ? xb[(size_t)c*Lseq + l] : 0.f;
    }
    __syncthreads();

    // ---- phase 1: in_proj GEMM with 8-deep register-pipelined Win loads ----
    float acc0[19], acc1[16];
    #pragma unroll
    for (int p=0;p<19;++p) acc0[p]=0.f;
    #pragma unroll
    for (int p=0;p<16;++p) acc1[p]=0.f;
    {
        const float* Wp = Win + t;
        float wa0[8], wa1[8], wb0[8], wb1[8];
        #pragma unroll
        for (int j=0;j<8;++j){ wa0[j]=Wp[j*512]; wa1[j]=Wp[j*512+256]; }
        #define KSTEP(kk, w0v, w1v) { \
            const float* xr = &xt[(kk)*20]; \
            float xv[19]; \
            _Pragma("unroll") \
            for (int p=0;p<19;++p) xv[p]=xr[p]; \
            _Pragma("unroll") \
            for (int p=0;p<19;++p) acc0[p]=fmaf(xv[p], (w0v), acc0[p]); \
            _Pragma("unroll") \
            for (int p=0;p<16;++p) acc1[p]=fmaf(xv[p+3], (w1v), acc1[p]); }
        for (int k0=0; k0<128; k0+=16){
            // issue loads for k0+8..k0+15 while computing k0..k0+7
            #pragma unroll
            for (int j=0;j<8;++j){ wb0[j]=Wp[(k0+8+j)*512]; wb1[j]=Wp[(k0+8+j)*512+256]; }
            #pragma unroll
            for (int j=0;j<8;++j) KSTEP(k0+j, wa0[j], wa1[j]);
            // issue loads for k0+16..k0+23 while computing k0+8..k0+15
            if (k0+16 < 128){
                #pragma unroll
                for (int j=0;j<8;++j){ wa0[j]=Wp[(k0+16+j)*512]; wa1[j]=Wp[(k0+16+j)*512+256]; }
            }
            #pragma unroll
            for (int j=0;j<8;++j) KSTEP(k0+8+j, wb0[j], wb1[j]);
        }
        #undef KSTEP
    }
    // z gate -> zs (coalesced: consecutive t -> consecutive addr)
    {
        float* zp = zs + ((size_t)(b*Lseq + l0))*DIN + t;
        #pragma unroll
        for (int p=0;p<16;++p) zp[p*DIN] = siluf(acc1[p]);
    }

    // ---- phase 2: causal depthwise conv + silu straight from acc0 registers ----
    {
        float cw0 = convw[t*4+0], cw1 = convw[t*4+1], cw2 = convw[t*4+2], cw3 = convw[t*4+3];
        float bb = convb[t];
        float* xcg = xc + ((size_t)(b*Lseq + l0))*DIN + t;
        #pragma unroll
        for (int l = 0; l < 16; ++l){
            float acc = bb;
            acc = fmaf(acc0[l],   cw0, acc);
            acc = fmaf(acc0[l+1], cw1, acc);
            acc = fmaf(acc0[l+2], cw2, acc);
            acc = fmaf(acc0[l+3], cw3, acc);
            float v = siluf(acc);
            xcs[l*257 + t] = v;
            xcg[l*DIN] = v;
        }
    }
    __syncthreads();

    // ---- phase 3: x_proj (128 active threads: 16 rows x 8 col-groups of 5) ----
    if (t < 128){
        int jg = t & 7;
        int lg = t >> 3;
        int j0 = jg * 5;
        float a0=0.f, a1=0.f, a2=0.f, a3=0.f, a4=0.f;
        const float* xrow = xcs + lg*257;
        const float* wbase = Wx + j0;
        #pragma unroll 8
        for (int d = 0; d < 256; ++d){
            float xv = xrow[d];
            const float* wr = wbase + d*40;
            a0 = fmaf(xv, wr[0], a0);
            a1 = fmaf(xv, wr[1], a1);
            a2 = fmaf(xv, wr[2], a2);
            a3 = fmaf(xv, wr[3], a3);
            a4 = fmaf(xv, wr[4], a4);
        }
        float* xo = xdbl + lg*40 + j0;
        xo[0]=a0; xo[1]=a1; xo[2]=a2; xo[3]=a3; xo[4]=a4;
    }
    __syncthreads();

    // ---- phase 4: dt_proj + softplus + fused scan pass 1 ----
    {
        float wd[DTR];
        #pragma unroll
        for (int r=0;r<DTR;++r) wd[r] = Wdt[r*DIN + t];
        float bv = bdt[t];
        float Av[16];
        {
            const float4* Ap = (const float4*)(Alog + t*DSTATE);
            #pragma unroll
            for (int q=0;q<4;++q){
                float4 a = Ap[q];
                Av[q*4]   = -__expf(a.x);
                Av[q*4+1] = -__expf(a.y);
                Av[q*4+2] = -__expf(a.z);
                Av[q*4+3] = -__expf(a.w);
            }
        }
        bool fastA = true;
        #pragma unroll
        for (int i=1;i<16;++i)
            fastA = fastA && (fabsf(Av[i] - (float)(i+1)*Av[0]) <= 1e-6f*fabsf(Av[i]));
        float P[16], S[16];
        #pragma unroll
        for (int s=0;s<16;++s){ P[s]=1.f; S[s]=0.f; }
        float* dtg = dt + ((size_t)(b*Lseq + l0))*DIN + t;
        #pragma unroll 4
        for (int l=0;l<16;++l){
            float a = bv;
            #pragma unroll
            for (int r=0;r<DTR;++r) a = fmaf(xdbl[l*40 + r], wd[r], a);
            float dtv = softplusf(a);
            dtg[l*DIN] = dtv;
            float xcv = xcs[l*257 + t];
            float dx  = dtv*xcv;
            const float4* Bv = (const float4*)&xdbl[l*40 + DTR];
            float4 B0 = Bv[0], B1 = Bv[1], B2 = Bv[2], B3 = Bv[3];
            float dAv[16];
            if (fastA){
                build_dA(__expf(dtv*Av[0]), dAv);
            } else {
                #pragma unroll
                for (int i=0;i<16;++i) dAv[i] = __expf(dtv*Av[i]);
            }
            #define ST1(i, bval) { P[i] *= dAv[i]; S[i] = fmaf(dAv[i], S[i], dx*(bval)); }
            ST1(0,B0.x) ST1(1,B0.y) ST1(2,B0.z) ST1(3,B0.w)
            ST1(4,B1.x) ST1(5,B1.y) ST1(6,B1.z) ST1(7,B1.w)
            ST1(8,B2.x) ST1(9,B2.y) ST1(10,B2.z) ST1(11,B2.w)
            ST1(12,B3.x) ST1(13,B3.y) ST1(14,B3.z) ST1(15,B3.w)
            #undef ST1
        }
        float2* ps = PSw + ((size_t)(b*NC + cb))*4096 + t*DSTATE;
        #pragma unroll
        for (int s=0;s<16;++s) ps[s] = make_float2(P[s], S[s]);
    }
    // ---- B/C extraction (16 l x 32 cols) ----
    for (int o = t; o < 512; o += 256){
        int l = o >> 5, q = o & 31;
        float v = xdbl[l*40 + DTR + q];
        size_t g = ((size_t)(b*Lseq + l0 + l))*DSTATE;
        if (q < DSTATE) Bm[g + q] = v;
        else            Cm[g + (q - DSTATE)] = v;
    }
}

// ---------------- Kernel C: pass 2, hierarchical chunk combine (round-2 measured version) ----------------
__global__ __launch_bounds__(256) void k_scan2(const float2* __restrict__ PSw,
        float* __restrict__ Iw){
    __shared__ float2 gps[16][16];
    __shared__ float  ge [16][16];
    int blk = blockIdx.x;               // 512 = b x 256 channel-groups of 16
    int b  = blk >> 8;
    int r0 = (blk & 255) * 16;
    int t  = threadIdx.x;
    int rr = t & 15;                    // channel within group
    int cg = t >> 4;                    // chunk-group 0..15 (16 chunks each)
    size_t base = ((size_t)(b*NC + cg*16))*4096 + r0 + rr;
    float Pl[16], Sl[16];
    float Pa = 1.f, Sa = 0.f;
    #pragma unroll
    for (int i=0;i<16;++i){
        float2 ps = PSw[base + (size_t)i*4096];
        Pl[i] = ps.x; Sl[i] = ps.y;
        Pa = ps.x * Pa;
        Sa = fmaf(ps.x, Sa, ps.y);
    }
    gps[cg][rr] = make_float2(Pa, Sa);
    __syncthreads();
    if (t < 16){
        float H = 0.f;
        #pragma unroll
        for (int g=0; g<16; ++g){
            float2 ps = gps[g][t];
            ge[g][t] = H;
            H = fmaf(ps.x, H, ps.y);
        }
    }
    __syncthreads();
    float H = ge[cg][rr];
    #pragma unroll
    for (int i=0;i<16;++i){
        Iw[base + (size_t)i*4096] = H;
        H = fmaf(Pl[i], H, Sl[i]);
    }
}

// ---------------- Kernel D: fused scan pass 3 + out_proj + LayerNorm + NCHW store -----------------------
// ROUND-2 measured structure + 8-deep register-pipelined Wout prefetch in the out_proj k-loop.
__global__ __launch_bounds__(256) void k_scan3out(const float* __restrict__ dt,
        const float* __restrict__ xc, const float* __restrict__ zs,
        const float* __restrict__ Bm, const float* __restrict__ Cm,
        const float* __restrict__ Alog, const float* __restrict__ Dv,
        const float* __restrict__ Iw,
        const float* __restrict__ Wout, const float* __restrict__ lng,
        const float* __restrict__ lnb, float* __restrict__ out){
    __shared__ float ysm[256*18];      // [d][l] stride 18
    __shared__ float os[128*18];       // [c][l] stride 18
    __shared__ float Bs[LC*DSTATE];    // 256
    __shared__ float Cs[LC*DSTATE];
    int blk = blockIdx.x;
    int b = blk >> 8, c = blk & 255;
    int l0 = c * LC;
    int t = threadIdx.x;               // = d in scan phase
    size_t gb = (size_t)(b*Lseq + l0);
    Bs[t] = Bm[gb*DSTATE + t];
    Cs[t] = Cm[gb*DSTATE + t];
    float Av[16];
    {
        const float4* Ap = (const float4*)(Alog + t*DSTATE);
        #pragma unroll
        for (int q=0;q<4;++q){
            float4 a = Ap[q];
            Av[q*4]   = -__expf(a.x);
            Av[q*4+1] = -__expf(a.y);
            Av[q*4+2] = -__expf(a.z);
            Av[q*4+3] = -__expf(a.w);
        }
    }
    bool fastA = true;
    #pragma unroll
    for (int i=1;i<16;++i)
        fastA = fastA && (fabsf(Av[i] - (float)(i+1)*Av[0]) <= 1e-6f*fabsf(Av[i]));
    float h[16];
    {
        const float4* Ip = (const float4*)(Iw + ((size_t)(b*NC + c))*4096 + t*DSTATE);
        #pragma unroll
        for (int q=0;q<4;++q){
            float4 v = Ip[q];
            h[q*4]=v.x; h[q*4+1]=v.y; h[q*4+2]=v.z; h[q*4+3]=v.w;
        }
    }
    float Dd = Dv[t];
    // register-stage all 48 loads (independent -> single latency window)
    float dtv[LC], xcv[LC], zvv[LC];
    {
        const float* dtp = dt + gb*DIN + t;
        const float* xcp = xc + gb*DIN + t;
        const float* zsp = zs + gb*DIN + t;
        #pragma unroll
        for (int l=0;l<LC;++l){
            dtv[l] = dtp[l*DIN];
            xcv[l] = xcp[l*DIN];
            zvv[l] = zsp[l*DIN];
        }
    }
    __syncthreads();
    #pragma unroll
    for (int l=0;l<LC;++l){
        float dtl = dtv[l];
        float dx  = dtl*xcv[l];
        const float4* Bv = (const float4*)&Bs[l*DSTATE];
        const float4* Cv = (const float4*)&Cs[l*DSTATE];
        float4 B0 = Bv[0], B1 = Bv[1], B2 = Bv[2], B3 = Bv[3];
        float4 C0 = Cv[0], C1 = Cv[1], C2 = Cv[2], C3 = Cv[3];
        float dAv[16];
        if (fastA){
            build_dA(__expf(dtl*Av[0]), dAv);
        } else {
            #pragma unroll
            for (int i=0;i<16;++i) dAv[i] = __expf(dtl*Av[i]);
        }
        float y = 0.f;
        #define ST3(i, bval, cval) { h[i] = fmaf(dAv[i], h[i], dx*(bval)); y = fmaf(h[i], (cval), y); }
        ST3(0,B0.x,C0.x) ST3(1,B0.y,C0.y) ST3(2,B0.z,C0.z) ST3(3,B0.w,C0.w)
        ST3(4,B1.x,C1.x) ST3(5,B1.y,C1.y) ST3(6,B1.z,C1.z) ST3(7,B1.w,C1.w)
        ST3(8,B2.x,C2.x) ST3(9,B2.y,C2.y) ST3(10,B2.z,C2.z) ST3(11,B2.w,C2.w)
        ST3(12,B3.x,C3.x) ST3(13,B3.y,C3.y) ST3(14,B3.z,C3.z) ST3(15,B3.w,C3.w)
        #undef ST3
        ysm[t*18 + l] = (y + Dd*xcv[l])*zvv[l];
    }
    __syncthreads();
    // ---- out_proj: 16l x 128c tile. lg=t>>5 -> l {lg*2, lg*2+1}; cg=t&31 -> 4 c.
    // 8-deep register-pipelined Wout float4 prefetch (two rolling halves of 8).
    int lg = t >> 5, cg = t & 31;
    int l0t = lg*2, c0 = cg*4;
    float acc[2][4];
    #pragma unroll
    for (int i=0;i<2;++i)
        #pragma unroll
        for (int j=0;j<4;++j) acc[i][j]=0.f;
    {
        const float* Wp = Wout + c0;
        float4 va[8], vb[8];
        #pragma unroll
        for (int j=0;j<8;++j) va[j] = *(const float4*)&Wp[j*OUTC];
        #define OSTEP(kk, wv) { \
            float2 yv = *(const float2*)&ysm[(kk)*18 + l0t]; \
            acc[0][0]=fmaf(yv.x,(wv).x,acc[0][0]); acc[0][1]=fmaf(yv.x,(wv).y,acc[0][1]); \
            acc[0][2]=fmaf(yv.x,(wv).z,acc[0][2]); acc[0][3]=fmaf(yv.x,(wv).w,acc[0][3]); \
            acc[1][0]=fmaf(yv.y,(wv).x,acc[1][0]); acc[1][1]=fmaf(yv.y,(wv).y,acc[1][1]); \
            acc[1][2]=fmaf(yv.y,(wv).z,acc[1][2]); acc[1][3]=fmaf(yv.y,(wv).w,acc[1][3]); }
        for (int k0=0; k0<DIN; k0+=16){
            #pragma unroll
            for (int j=0;j<8;++j) vb[j] = *(const float4*)&Wp[(k0+8+j)*OUTC];
            #pragma unroll
            for (int j=0;j<8;++j) OSTEP(k0+j, va[j]);
            if (k0+16 < DIN){
                #pragma unroll
                for (int j=0;j<8;++j) va[j] = *(const float4*)&Wp[(k0+16+j)*OUTC];
            }
            #pragma unroll
            for (int j=0;j<8;++j) OSTEP(k0+8+j, vb[j]);
        }
        #undef OSTEP
    }
    // LayerNorm over c: reduce across the 32 lanes sharing this l (xor<=16 stays in half-wave)
    float4 gm = *(const float4*)&lng[c0];
    float4 bt = *(const float4*)&lnb[c0];
    #pragma unroll
    for (int i=0;i<2;++i){
        float rs = acc[i][0]+acc[i][1]+acc[i][2]+acc[i][3];
        #pragma unroll
        for (int m=16;m>0;m>>=1) rs += __shfl_xor(rs, m, 64);
        float mu = rs * (1.f/128.f);
        float d0 = acc[i][0]-mu, d1 = acc[i][1]-mu, d2 = acc[i][2]-mu, d3 = acc[i][3]-mu;
        float sq = d0*d0+d1*d1+d2*d2+d3*d3;
        #pragma unroll
        for (int m=16;m>0;m>>=1) sq += __shfl_xor(sq, m, 64);
        float rstd = rsqrtf(sq * (1.f/128.f) + 1e-5f);
        int lidx = l0t + i;
        os[(c0+0)*18 + lidx] = d0*rstd*gm.x + bt.x;
        os[(c0+1)*18 + lidx] = d1*rstd*gm.y + bt.y;
        os[(c0+2)*18 + lidx] = d2*rstd*gm.z + bt.z;
        os[(c0+3)*18 + lidx] = d3*rstd*gm.w + bt.w;
    }
    __syncthreads();
    // store: cc = t>>1 (0..127), sel = t&1 -> 8 consecutive l = 32B per lane; full 64B lines per c
    {
        int cc = t >> 1, sel = t & 1;
        const float* ip = &os[cc*18 + sel*8];
        float2 a0 = *(const float2*)(ip);
        float2 a1 = *(const float2*)(ip+2);
        float2 a2 = *(const float2*)(ip+4);
        float2 a3 = *(const float2*)(ip+6);
        float* op = out + ((size_t)(b*OUTC + cc))*Lseq + l0 + sel*8;
        *(float4*)(op)   = make_float4(a0.x,a0.y,a1.x,a1.y);
        *(float4*)(op+4) = make_float4(a2.x,a2.y,a3.x,a3.y);
    }
}

extern "C" void kernel_launch(void* const* d_in, const int* in_sizes, int n_in,
                              void* d_out, int out_size, void* d_ws, size_t ws_size,
                              hipStream_t stream) {
    const float* x1    = (const float*)d_in[0];
    const float* Win   = (const float*)d_in[1];
    const float* convw = (const float*)d_in[2];
    const float* convb = (const float*)d_in[3];
    const float* Wx    = (const float*)d_in[4];
    const float* Wdt   = (const float*)d_in[5];
    const float* bdt   = (const float*)d_in[6];
    const float* Alog  = (const float*)d_in[7];
    const float* Dv    = (const float*)d_in[8];
    const float* Wout  = (const float*)d_in[9];
    const float* lng   = (const float*)d_in[10];
    const float* lnb   = (const float*)d_in[11];
    float* out = (float*)d_out;

    float* ws  = (float*)d_ws;
    float* Iw  = ws;                        // 2,097,152 floats (entry states, written by scan2)
    float* zs  = Iw  + 2097152;             // 2,097,152
    float* xc  = zs  + 2097152;             // 2,097,152
    float* dt  = xc  + 2097152;             // 2,097,152
    float* Bm  = dt  + 2097152;             //   131,072
    float* Cm  = Bm  + 131072;              //   131,072
    float2* PSw = (float2*)(Cm + 131072);   // 2,097,152 float2 (~51.4 MB total)

    k_inconv_scan1<<<512, 256, 0, stream>>>(x1, Win, convw, convb, Wx, Wdt, bdt, Alog,
                                            zs, xc, dt, Bm, Cm, PSw);
    k_scan2       <<<512, 256, 0, stream>>>(PSw, Iw);
    k_scan3out    <<<512, 256, 0, stream>>>(dt, xc, zs, Bm, Cm, Alog, Dv, Iw,
                                            Wout, lng, lnb, out);
}

// Round 8
// 158.277 us; speedup vs baseline: 1.5492x; 1.1813x over previous
//
#include <hip/hip_runtime.h>
#include <math.h>

#define B_ 2
#define DMODEL 128
#define DIN 256
#define DSTATE 16
#define DTR 8
#define OUTC 128
#define Lseq 4096
#define NC 256          // chunks per batch
#define LC 16           // timesteps per chunk

__device__ __forceinline__ float siluf(float x){ return x / (1.f + __expf(-x)); }

// dA[s] = e1^(s+1), s=0..15, via log-depth power ladder (15 muls, depth ~4).
__device__ __forceinline__ void build_dA(float e1, float* dAv){
    float e2 = e1*e1, e4 = e2*e2, e8 = e4*e4;
    dAv[0]=e1;         dAv[1]=e2;         dAv[2]=e2*e1;       dAv[3]=e4;
    dAv[4]=e4*e1;      dAv[5]=e4*e2;      dAv[6]=e4*dAv[2];   dAv[7]=e8;
    dAv[8]=e8*e1;      dAv[9]=e8*e2;      dAv[10]=e8*dAv[2];  dAv[11]=e8*e4;
    dAv[12]=e8*dAv[4]; dAv[13]=e8*dAv[5]; dAv[14]=e8*dAv[6];  dAv[15]=e8*e8;
}

__device__ __forceinline__ float softplusf(float a){
    return (a > 20.f) ? a : __logf(1.f + __expf(a));
}

// ---------------- Kernel AB (fused): in_proj + conv + silu + x_proj + dt_proj + scan pass 1 --------------
// EXACT Round-2 structure (measured best: 63 us) with ONE change: Wx (256x40 = 40KB) is staged into LDS
// (reusing the dead xt buffer region) after the conv phase, so phase 3's 1280 strided global loads/thread
// become LDS broadcast reads. No VGPR-affecting restructure anywhere else.
__global__ __launch_bounds__(256) void k_inconv_scan1(const float* __restrict__ x1,
        const float* __restrict__ Win,
        const float* __restrict__ convw, const float* __restrict__ convb,
        const float* __restrict__ Wx, const float* __restrict__ Wdt,
        const float* __restrict__ bdt, const float* __restrict__ Alog,
        float* __restrict__ zs, float* __restrict__ xc, float* __restrict__ dt,
        float* __restrict__ Bm, float* __restrict__ Cm, float2* __restrict__ PSw){
    __shared__ float sbuf[10240];      // union: phase 0-1 = xt[128*20] (2560 used); phase 3+ = Wxs[256*40]
    __shared__ float xcs[16*257];      // conv output [l][d]
    __shared__ float xdbl[16*40];      // x_proj output [l][40]
    float* xt  = sbuf;                 // x tile [c][p], p=0..18 -> l = l0-3+p (pad stride 20)
    float* Wxs = sbuf;                 // Wx staged [d][j], stride 40 (d=0..255, j=0..39)
    int blk = blockIdx.x;              // 512 = b x 256 chunks
    int b  = blk >> 8;
    int cb = blk & 255;
    int l0 = cb << 4;
    int t  = threadIdx.x;

    // ---- phase 0: stage x tile (19 timesteps incl. 3-l causal halo, zeros at l<0) ----
    const float* xb = x1 + (size_t)b * DMODEL * Lseq;
    for (int e = t; e < 128*19; e += 256){
        int c = e / 19, p = e - c*19;
        int l = l0 - 3 + p;
        xt[c*20 + p] = (l >= 0) ? xb[(size_t)c*Lseq + l] : 0.f;
    }
    __syncthreads();

    // ---- phase 1: in_proj GEMM. thread t -> xin col t (19 p incl halo) + z col t (16 p) ----
    float acc0[19], acc1[16];
    #pragma unroll
    for (int p=0;p<19;++p){acc0[p]=0.f;}
    #pragma unroll
    for (int p=0;p<16;++p){acc1[p]=0.f;}
    #pragma unroll 4
    for (int k=0;k<DMODEL;++k){
        float w0 = Win[k*512 + t];
        float w1 = Win[k*512 + t + 256];
        float xv[19];
        #pragma unroll
        for (int p=0;p<19;++p) xv[p] = xt[k*20 + p];
        #pragma unroll
        for (int p=0;p<19;++p) acc0[p] = fmaf(xv[p], w0, acc0[p]);
        #pragma unroll
        for (int p=0;p<16;++p) acc1[p] = fmaf(xv[p+3], w1, acc1[p]);
    }
    // z gate -> zs (coalesced: consecutive t -> consecutive addr)
    {
        float* zp = zs + ((size_t)(b*Lseq + l0))*DIN + t;
        #pragma unroll
        for (int p=0;p<16;++p) zp[p*DIN] = siluf(acc1[p]);
    }

    // ---- phase 2: causal depthwise conv + silu straight from acc0 registers ----
    {
        float cw0 = convw[t*4+0], cw1 = convw[t*4+1], cw2 = convw[t*4+2], cw3 = convw[t*4+3];
        float bb = convb[t];
        float* xcg = xc + ((size_t)(b*Lseq + l0))*DIN + t;
        #pragma unroll
        for (int l = 0; l < 16; ++l){
            float acc = bb;
            acc = fmaf(acc0[l],   cw0, acc);
            acc = fmaf(acc0[l+1], cw1, acc);
            acc = fmaf(acc0[l+2], cw2, acc);
            acc = fmaf(acc0[l+3], cw3, acc);
            float v = siluf(acc);
            xcs[l*257 + t] = v;
            xcg[l*DIN] = v;
        }
    }
    __syncthreads();                   // all waves done reading xt

    // ---- phase 2.5: stage Wx into LDS (coalesced float4: 2560 float4 / 256 thr = 10 each) ----
    {
        const float4* Wg = (const float4*)Wx;
        float4* Ws = (float4*)Wxs;
        #pragma unroll
        for (int e = t; e < 2560; e += 256)
            Ws[e] = Wg[e];
    }
    __syncthreads();

    // ---- phase 3: x_proj from LDS (128 active threads: 16 rows x 8 col-groups of 5) ----
    if (t < 128){
        int jg = t & 7;
        int lg = t >> 3;
        int j0 = jg * 5;
        float a0=0.f, a1=0.f, a2=0.f, a3=0.f, a4=0.f;
        const float* xrow = xcs + lg*257;
        const float* wbase = Wxs + j0;
        #pragma unroll 8
        for (int d = 0; d < 256; ++d){
            float xv = xrow[d];
            const float* wr = wbase + d*40;
            a0 = fmaf(xv, wr[0], a0);
            a1 = fmaf(xv, wr[1], a1);
            a2 = fmaf(xv, wr[2], a2);
            a3 = fmaf(xv, wr[3], a3);
            a4 = fmaf(xv, wr[4], a4);
        }
        float* xo = xdbl + lg*40 + j0;
        xo[0]=a0; xo[1]=a1; xo[2]=a2; xo[3]=a3; xo[4]=a4;
    }
    __syncthreads();

    // ---- phase 4: dt_proj + softplus + fused scan pass 1 ----
    {
        float wd[DTR];
        #pragma unroll
        for (int r=0;r<DTR;++r) wd[r] = Wdt[r*DIN + t];
        float bv = bdt[t];
        float Av[16];
        {
            const float4* Ap = (const float4*)(Alog + t*DSTATE);
            #pragma unroll
            for (int q=0;q<4;++q){
                float4 a = Ap[q];
                Av[q*4]   = -__expf(a.x);
                Av[q*4+1] = -__expf(a.y);
                Av[q*4+2] = -__expf(a.z);
                Av[q*4+3] = -__expf(a.w);
            }
        }
        bool fastA = true;
        #pragma unroll
        for (int i=1;i<16;++i)
            fastA = fastA && (fabsf(Av[i] - (float)(i+1)*Av[0]) <= 1e-6f*fabsf(Av[i]));
        float P[16], S[16];
        #pragma unroll
        for (int s=0;s<16;++s){ P[s]=1.f; S[s]=0.f; }
        float* dtg = dt + ((size_t)(b*Lseq + l0))*DIN + t;
        #pragma unroll 4
        for (int l=0;l<16;++l){
            float a = bv;
            #pragma unroll
            for (int r=0;r<DTR;++r) a = fmaf(xdbl[l*40 + r], wd[r], a);
            float dtv = softplusf(a);
            dtg[l*DIN] = dtv;
            float xcv = xcs[l*257 + t];
            float dx  = dtv*xcv;
            const float4* Bv = (const float4*)&xdbl[l*40 + DTR];
            float4 B0 = Bv[0], B1 = Bv[1], B2 = Bv[2], B3 = Bv[3];
            float dAv[16];
            if (fastA){
                build_dA(__expf(dtv*Av[0]), dAv);
            } else {
                #pragma unroll
                for (int i=0;i<16;++i) dAv[i] = __expf(dtv*Av[i]);
            }
            #define ST1(i, bval) { P[i] *= dAv[i]; S[i] = fmaf(dAv[i], S[i], dx*(bval)); }
            ST1(0,B0.x) ST1(1,B0.y) ST1(2,B0.z) ST1(3,B0.w)
            ST1(4,B1.x) ST1(5,B1.y) ST1(6,B1.z) ST1(7,B1.w)
            ST1(8,B2.x) ST1(9,B2.y) ST1(10,B2.z) ST1(11,B2.w)
            ST1(12,B3.x) ST1(13,B3.y) ST1(14,B3.z) ST1(15,B3.w)
            #undef ST1
        }
        float2* ps = PSw + ((size_t)(b*NC + cb))*4096 + t*DSTATE;
        #pragma unroll
        for (int s=0;s<16;++s) ps[s] = make_float2(P[s], S[s]);
    }
    // ---- B/C extraction (16 l x 32 cols) ----
    for (int o = t; o < 1024; o += 256){
        int l = o >> 5, q = o & 31;
        float v = xdbl[l*40 + DTR + q];
        size_t g = ((size_t)(b*Lseq + l0 + l))*DSTATE;
        if (q < DSTATE) Bm[g + q] = v;
        else            Cm[g + (q - DSTATE)] = v;
    }
}

// ---------------- Kernel C: pass 2, hierarchical chunk combine (round-2 measured version) ----------------
__global__ __launch_bounds__(256) void k_scan2(const float2* __restrict__ PSw,
        float* __restrict__ Iw){
    __shared__ float2 gps[16][16];
    __shared__ float  ge [16][16];
    int blk = blockIdx.x;               // 512 = b x 256 channel-groups of 16
    int b  = blk >> 8;
    int r0 = (blk & 255) * 16;
    int t  = threadIdx.x;
    int rr = t & 15;                    // channel within group
    int cg = t >> 4;                    // chunk-group 0..15 (16 chunks each)
    size_t base = ((size_t)(b*NC + cg*16))*4096 + r0 + rr;
    float Pl[16], Sl[16];
    float Pa = 1.f, Sa = 0.f;
    #pragma unroll
    for (int i=0;i<16;++i){
        float2 ps = PSw[base + (size_t)i*4096];
        Pl[i] = ps.x; Sl[i] = ps.y;
        Pa = ps.x * Pa;
        Sa = fmaf(ps.x, Sa, ps.y);
    }
    gps[cg][rr] = make_float2(Pa, Sa);
    __syncthreads();
    if (t < 16){
        float H = 0.f;
        #pragma unroll
        for (int g=0; g<16; ++g){
            float2 ps = gps[g][t];
            ge[g][t] = H;
            H = fmaf(ps.x, H, ps.y);
        }
    }
    __syncthreads();
    float H = ge[cg][rr];
    #pragma unroll
    for (int i=0;i<16;++i){
        Iw[base + (size_t)i*4096] = H;
        H = fmaf(Pl[i], H, Sl[i]);
    }
}

// ---------------- Kernel D: fused scan pass 3 + out_proj + LayerNorm + NCHW store -----------------------
// EXACT round-2 measured version (no prefetch experiments).
__global__ __launch_bounds__(256) void k_scan3out(const float* __restrict__ dt,
        const float* __restrict__ xc, const float* __restrict__ zs,
        const float* __restrict__ Bm, const float* __restrict__ Cm,
        const float* __restrict__ Alog, const float* __restrict__ Dv,
        const float* __restrict__ Iw,
        const float* __restrict__ Wout, const float* __restrict__ lng,
        const float* __restrict__ lnb, float* __restrict__ out){
    __shared__ float ysm[256*18];      // [d][l] stride 18
    __shared__ float os[128*18];       // [c][l] stride 18
    __shared__ float Bs[LC*DSTATE];    // 256
    __shared__ float Cs[LC*DSTATE];
    int blk = blockIdx.x;
    int b = blk >> 8, c = blk & 255;
    int l0 = c * LC;
    int t = threadIdx.x;               // = d in scan phase
    size_t gb = (size_t)(b*Lseq + l0);
    Bs[t] = Bm[gb*DSTATE + t];
    Cs[t] = Cm[gb*DSTATE + t];
    float Av[16];
    {
        const float4* Ap = (const float4*)(Alog + t*DSTATE);
        #pragma unroll
        for (int q=0;q<4;++q){
            float4 a = Ap[q];
            Av[q*4]   = -__expf(a.x);
            Av[q*4+1] = -__expf(a.y);
            Av[q*4+2] = -__expf(a.z);
            Av[q*4+3] = -__expf(a.w);
        }
    }
    bool fastA = true;
    #pragma unroll
    for (int i=1;i<16;++i)
        fastA = fastA && (fabsf(Av[i] - (float)(i+1)*Av[0]) <= 1e-6f*fabsf(Av[i]));
    float h[16];
    {
        const float4* Ip = (const float4*)(Iw + ((size_t)(b*NC + c))*4096 + t*DSTATE);
        #pragma unroll
        for (int q=0;q<4;++q){
            float4 v = Ip[q];
            h[q*4]=v.x; h[q*4+1]=v.y; h[q*4+2]=v.z; h[q*4+3]=v.w;
        }
    }
    float Dd = Dv[t];
    // register-stage all 48 loads (independent -> single latency window)
    float dtv[LC], xcv[LC], zvv[LC];
    {
        const float* dtp = dt + gb*DIN + t;
        const float* xcp = xc + gb*DIN + t;
        const float* zsp = zs + gb*DIN + t;
        #pragma unroll
        for (int l=0;l<LC;++l){
            dtv[l] = dtp[l*DIN];
            xcv[l] = xcp[l*DIN];
            zvv[l] = zsp[l*DIN];
        }
    }
    __syncthreads();
    #pragma unroll
    for (int l=0;l<LC;++l){
        float dtl = dtv[l];
        float dx  = dtl*xcv[l];
        const float4* Bv = (const float4*)&Bs[l*DSTATE];
        const float4* Cv = (const float4*)&Cs[l*DSTATE];
        float4 B0 = Bv[0], B1 = Bv[1], B2 = Bv[2], B3 = Bv[3];
        float4 C0 = Cv[0], C1 = Cv[1], C2 = Cv[2], C3 = Cv[3];
        float dAv[16];
        if (fastA){
            build_dA(__expf(dtl*Av[0]), dAv);
        } else {
            #pragma unroll
            for (int i=0;i<16;++i) dAv[i] = __expf(dtl*Av[i]);
        }
        float y = 0.f;
        #define ST3(i, bval, cval) { h[i] = fmaf(dAv[i], h[i], dx*(bval)); y = fmaf(h[i], (cval), y); }
        ST3(0,B0.x,C0.x) ST3(1,B0.y,C0.y) ST3(2,B0.z,C0.z) ST3(3,B0.w,C0.w)
        ST3(4,B1.x,C1.x) ST3(5,B1.y,C1.y) ST3(6,B1.z,C1.z) ST3(7,B1.w,C1.w)
        ST3(8,B2.x,C2.x) ST3(9,B2.y,C2.y) ST3(10,B2.z,C2.z) ST3(11,B2.w,C2.w)
        ST3(12,B3.x,C3.x) ST3(13,B3.y,C3.y) ST3(14,B3.z,C3.z) ST3(15,B3.w,C3.w)
        #undef ST3
        ysm[t*18 + l] = (y + Dd*xcv[l])*zvv[l];
    }
    __syncthreads();
    // ---- out_proj: 16l x 128c tile. lg=t>>5 -> l {lg*2, lg*2+1}; cg=t&31 -> 4 c.
    int lg = t >> 5, cg = t & 31;
    int l0t = lg*2, c0 = cg*4;
    float acc[2][4];
    #pragma unroll
    for (int i=0;i<2;++i)
        #pragma unroll
        for (int j=0;j<4;++j) acc[i][j]=0.f;
    #pragma unroll 4
    for (int k=0;k<DIN;++k){
        float2 yv = *(const float2*)&ysm[k*18 + l0t];
        float4 wv = *(const float4*)&Wout[k*OUTC + c0];
        acc[0][0]=fmaf(yv.x,wv.x,acc[0][0]); acc[0][1]=fmaf(yv.x,wv.y,acc[0][1]);
        acc[0][2]=fmaf(yv.x,wv.z,acc[0][2]); acc[0][3]=fmaf(yv.x,wv.w,acc[0][3]);
        acc[1][0]=fmaf(yv.y,wv.x,acc[1][0]); acc[1][1]=fmaf(yv.y,wv.y,acc[1][1]);
        acc[1][2]=fmaf(yv.y,wv.z,acc[1][2]); acc[1][3]=fmaf(yv.y,wv.w,acc[1][3]);
    }
    // LayerNorm over c: reduce across the 32 lanes sharing this l (xor<=16 stays in half-wave)
    float4 gm = *(const float4*)&lng[c0];
    float4 bt = *(const float4*)&lnb[c0];
    #pragma unroll
    for (int i=0;i<2;++i){
        float rs = acc[i][0]+acc[i][1]+acc[i][2]+acc[i][3];
        #pragma unroll
        for (int m=16;m>0;m>>=1) rs += __shfl_xor(rs, m, 64);
        float mu = rs * (1.f/128.f);
        float d0 = acc[i][0]-mu, d1 = acc[i][1]-mu, d2 = acc[i][2]-mu, d3 = acc[i][3]-mu;
        float sq = d0*d0+d1*d1+d2*d2+d3*d3;
        #pragma unroll
        for (int m=16;m>0;m>>=1) sq += __shfl_xor(sq, m, 64);
        float rstd = rsqrtf(sq * (1.f/128.f) + 1e-5f);
        int lidx = l0t + i;
        os[(c0+0)*18 + lidx] = d0*rstd*gm.x + bt.x;
        os[(c0+1)*18 + lidx] = d1*rstd*gm.y + bt.y;
        os[(c0+2)*18 + lidx] = d2*rstd*gm.z + bt.z;
        os[(c0+3)*18 + lidx] = d3*rstd*gm.w + bt.w;
    }
    __syncthreads();
    // store: cc = t>>1 (0..127), sel = t&1 -> 8 consecutive l = 32B per lane; full 64B lines per c
    {
        int cc = t >> 1, sel = t & 1;
        const float* ip = &os[cc*18 + sel*8];
        float2 a0 = *(const float2*)(ip);
        float2 a1 = *(const float2*)(ip+2);
        float2 a2 = *(const float2*)(ip+4);
        float2 a3 = *(const float2*)(ip+6);
        float* op = out + ((size_t)(b*OUTC + cc))*Lseq + l0 + sel*8;
        *(float4*)(op)   = make_float4(a0.x,a0.y,a1.x,a1.y);
        *(float4*)(op+4) = make_float4(a2.x,a2.y,a3.x,a3.y);
    }
}

extern "C" void kernel_launch(void* const* d_in, const int* in_sizes, int n_in,
                              void* d_out, int out_size, void* d_ws, size_t ws_size,
                              hipStream_t stream) {
    const float* x1    = (const float*)d_in[0];
    const float* Win   = (const float*)d_in[1];
    const float* convw = (const float*)d_in[2];
    const float* convb = (const float*)d_in[3];
    const float* Wx    = (const float*)d_in[4];
    const float* Wdt   = (const float*)d_in[5];
    const float* bdt   = (const float*)d_in[6];
    const float* Alog  = (const float*)d_in[7];
    const float* Dv    = (const float*)d_in[8];
    const float* Wout  = (const float*)d_in[9];
    const float* lng   = (const float*)d_in[10];
    const float* lnb   = (const float*)d_in[11];
    float* out = (float*)d_out;

    float* ws  = (float*)d_ws;
    float* Iw  = ws;                        // 2,097,152 floats (entry states, written by scan2)
    float* zs  = Iw  + 2097152;             // 2,097,152
    float* xc  = zs  + 2097152;             // 2,097,152
    float* dt  = xc  + 2097152;             // 2,097,152
    float* Bm  = dt  + 2097152;             //   131,072
    float* Cm  = Bm  + 131072;              //   131,072
    float2* PSw = (float2*)(Cm + 131072);   // 2,097,152 float2 (~51.4 MB total)

    k_inconv_scan1<<<512, 256, 0, stream>>>(x1, Win, convw, convb, Wx, Wdt, bdt, Alog,
                                            zs, xc, dt, Bm, Cm, PSw);
    k_scan2       <<<512, 256, 0, stream>>>(PSw, Iw);
    k_scan3out    <<<512, 256, 0, stream>>>(dt, xc, zs, Bm, Cm, Alog, Dv, Iw,
                                            Wout, lng, lnb, out);
}

// Round 11
// 157.321 us; speedup vs baseline: 1.5586x; 1.0061x over previous
//
#include <hip/hip_runtime.h>
#include <math.h>

#define B_ 2
#define DMODEL 128
#define DIN 256
#define DSTATE 16
#define DTR 8
#define OUTC 128
#define Lseq 4096
#define NC 256          // chunks per batch
#define LC 16           // timesteps per chunk

__device__ __forceinline__ float siluf(float x){ return x / (1.f + __expf(-x)); }

// dA[s] = e1^(s+1), s=0..15, via log-depth power ladder (15 muls, depth ~4).
__device__ __forceinline__ void build_dA(float e1, float* dAv){
    float e2 = e1*e1, e4 = e2*e2, e8 = e4*e4;
    dAv[0]=e1;         dAv[1]=e2;         dAv[2]=e2*e1;       dAv[3]=e4;
    dAv[4]=e4*e1;      dAv[5]=e4*e2;      dAv[6]=e4*dAv[2];   dAv[7]=e8;
    dAv[8]=e8*e1;      dAv[9]=e8*e2;      dAv[10]=e8*dAv[2];  dAv[11]=e8*e4;
    dAv[12]=e8*dAv[4]; dAv[13]=e8*dAv[5]; dAv[14]=e8*dAv[6];  dAv[15]=e8*e8;
}

__device__ __forceinline__ float softplusf(float a){
    return (a > 20.f) ? a : __logf(1.f + __expf(a));
}

// ---------------- Kernel AB (fused): in_proj + conv + silu + x_proj + dt_proj + scan pass 1 --------------
// Round-8 structure (Wx->LDS staging, measured 53 us) + three fixes:
//  (1) BUGFIX: B/C extraction o<512 (o<1024 raced into the next chunk's Bm/Cm with OOB-LDS garbage)
//  (2) phase-1 xt reads as float4 (5 ds_read_b128/k instead of 19 ds_read_b32/k)
//  (3) PSw per-chunk layout [s][d]: 16 coalesced 512B stores instead of 16 64-line scattered stores
__global__ __launch_bounds__(256) void k_inconv_scan1(const float* __restrict__ x1,
        const float* __restrict__ Win,
        const float* __restrict__ convw, const float* __restrict__ convb,
        const float* __restrict__ Wx, const float* __restrict__ Wdt,
        const float* __restrict__ bdt, const float* __restrict__ Alog,
        float* __restrict__ zs, float* __restrict__ xc, float* __restrict__ dt,
        float* __restrict__ Bm, float* __restrict__ Cm, float2* __restrict__ PSw){
    __shared__ float sbuf[10240];      // union: phase 0-1 = xt[128*20] (2560 used); phase 3+ = Wxs[256*40]
    __shared__ float xcs[16*257];      // conv output [l][d]
    __shared__ float xdbl[16*40];      // x_proj output [l][40]
    float* xt  = sbuf;                 // x tile [c][p], p=0..18 -> l = l0-3+p (pad stride 20; 80B rows, 16B-aligned)
    float* Wxs = sbuf;                 // Wx staged [d][j], stride 40 (d=0..255, j=0..39)
    int blk = blockIdx.x;              // 512 = b x 256 chunks
    int b  = blk >> 8;
    int cb = blk & 255;
    int l0 = cb << 4;
    int t  = threadIdx.x;

    // ---- phase 0: stage x tile (19 timesteps incl. 3-l causal halo, zeros at l<0) ----
    const float* xb = x1 + (size_t)b * DMODEL * Lseq;
    for (int e = t; e < 128*19; e += 256){
        int c = e / 19, p = e - c*19;
        int l = l0 - 3 + p;
        xt[c*20 + p] = (l >= 0) ? xb[(size_t)c*Lseq + l] : 0.f;
    }
    __syncthreads();

    // ---- phase 1: in_proj GEMM. thread t -> xin col t (19 p incl halo) + z col t (16 p) ----
    float acc0[19], acc1[16];
    #pragma unroll
    for (int p=0;p<19;++p){acc0[p]=0.f;}
    #pragma unroll
    for (int p=0;p<16;++p){acc1[p]=0.f;}
    #pragma unroll 4
    for (int k=0;k<DMODEL;++k){
        float w0 = Win[k*512 + t];
        float w1 = Win[k*512 + t + 256];
        const float4* xp = (const float4*)&xt[k*20];
        float4 v0 = xp[0], v1 = xp[1], v2 = xp[2], v3 = xp[3], v4 = xp[4];
        float xv[19] = { v0.x,v0.y,v0.z,v0.w, v1.x,v1.y,v1.z,v1.w,
                         v2.x,v2.y,v2.z,v2.w, v3.x,v3.y,v3.z,v3.w,
                         v4.x,v4.y,v4.z };
        #pragma unroll
        for (int p=0;p<19;++p) acc0[p] = fmaf(xv[p], w0, acc0[p]);
        #pragma unroll
        for (int p=0;p<16;++p) acc1[p] = fmaf(xv[p+3], w1, acc1[p]);
    }
    // z gate -> zs (coalesced: consecutive t -> consecutive addr)
    {
        float* zp = zs + ((size_t)(b*Lseq + l0))*DIN + t;
        #pragma unroll
        for (int p=0;p<16;++p) zp[p*DIN] = siluf(acc1[p]);
    }

    // ---- phase 2: causal depthwise conv + silu straight from acc0 registers ----
    {
        float cw0 = convw[t*4+0], cw1 = convw[t*4+1], cw2 = convw[t*4+2], cw3 = convw[t*4+3];
        float bb = convb[t];
        float* xcg = xc + ((size_t)(b*Lseq + l0))*DIN + t;
        #pragma unroll
        for (int l = 0; l < 16; ++l){
            float acc = bb;
            acc = fmaf(acc0[l],   cw0, acc);
            acc = fmaf(acc0[l+1], cw1, acc);
            acc = fmaf(acc0[l+2], cw2, acc);
            acc = fmaf(acc0[l+3], cw3, acc);
            float v = siluf(acc);
            xcs[l*257 + t] = v;
            xcg[l*DIN] = v;
        }
    }
    __syncthreads();                   // all waves done reading xt

    // ---- phase 2.5: stage Wx into LDS (coalesced float4: 2560 float4 / 256 thr = 10 each) ----
    {
        const float4* Wg = (const float4*)Wx;
        float4* Ws = (float4*)Wxs;
        #pragma unroll
        for (int e = t; e < 2560; e += 256)
            Ws[e] = Wg[e];
    }
    __syncthreads();

    // ---- phase 3: x_proj from LDS (128 active threads: 16 rows x 8 col-groups of 5) ----
    if (t < 128){
        int jg = t & 7;
        int lg = t >> 3;
        int j0 = jg * 5;
        float a0=0.f, a1=0.f, a2=0.f, a3=0.f, a4=0.f;
        const float* xrow = xcs + lg*257;
        const float* wbase = Wxs + j0;
        #pragma unroll 8
        for (int d = 0; d < 256; ++d){
            float xv = xrow[d];
            const float* wr = wbase + d*40;
            a0 = fmaf(xv, wr[0], a0);
            a1 = fmaf(xv, wr[1], a1);
            a2 = fmaf(xv, wr[2], a2);
            a3 = fmaf(xv, wr[3], a3);
            a4 = fmaf(xv, wr[4], a4);
        }
        float* xo = xdbl + lg*40 + j0;
        xo[0]=a0; xo[1]=a1; xo[2]=a2; xo[3]=a3; xo[4]=a4;
    }
    __syncthreads();

    // ---- phase 4: dt_proj + softplus + fused scan pass 1 ----
    {
        float wd[DTR];
        #pragma unroll
        for (int r=0;r<DTR;++r) wd[r] = Wdt[r*DIN + t];
        float bv = bdt[t];
        float Av[16];
        {
            const float4* Ap = (const float4*)(Alog + t*DSTATE);
            #pragma unroll
            for (int q=0;q<4;++q){
                float4 a = Ap[q];
                Av[q*4]   = -__expf(a.x);
                Av[q*4+1] = -__expf(a.y);
                Av[q*4+2] = -__expf(a.z);
                Av[q*4+3] = -__expf(a.w);
            }
        }
        bool fastA = true;
        #pragma unroll
        for (int i=1;i<16;++i)
            fastA = fastA && (fabsf(Av[i] - (float)(i+1)*Av[0]) <= 1e-6f*fabsf(Av[i]));
        float P[16], S[16];
        #pragma unroll
        for (int s=0;s<16;++s){ P[s]=1.f; S[s]=0.f; }
        float* dtg = dt + ((size_t)(b*Lseq + l0))*DIN + t;
        #pragma unroll 4
        for (int l=0;l<16;++l){
            float a = bv;
            #pragma unroll
            for (int r=0;r<DTR;++r) a = fmaf(xdbl[l*40 + r], wd[r], a);
            float dtv = softplusf(a);
            dtg[l*DIN] = dtv;
            float xcv = xcs[l*257 + t];
            float dx  = dtv*xcv;
            const float4* Bv = (const float4*)&xdbl[l*40 + DTR];
            float4 B0 = Bv[0], B1 = Bv[1], B2 = Bv[2], B3 = Bv[3];
            float dAv[16];
            if (fastA){
                build_dA(__expf(dtv*Av[0]), dAv);
            } else {
                #pragma unroll
                for (int i=0;i<16;++i) dAv[i] = __expf(dtv*Av[i]);
            }
            #define ST1(i, bval) { P[i] *= dAv[i]; S[i] = fmaf(dAv[i], S[i], dx*(bval)); }
            ST1(0,B0.x) ST1(1,B0.y) ST1(2,B0.z) ST1(3,B0.w)
            ST1(4,B1.x) ST1(5,B1.y) ST1(6,B1.z) ST1(7,B1.w)
            ST1(8,B2.x) ST1(9,B2.y) ST1(10,B2.z) ST1(11,B2.w)
            ST1(12,B3.x) ST1(13,B3.y) ST1(14,B3.z) ST1(15,B3.w)
            #undef ST1
        }
        // PSw per-chunk layout [s][d]: ps2[s*256 + t] -> consecutive lanes = consecutive float2 (coalesced)
        float2* ps2 = PSw + ((size_t)(b*NC + cb))*4096;
        #pragma unroll
        for (int s=0;s<16;++s) ps2[s*256 + t] = make_float2(P[s], S[s]);
    }
    // ---- B/C extraction (16 l x 32 cols = 512 elements) — o < 512 (BUGFIX: was 1024, OOB+race) ----
    for (int o = t; o < 512; o += 256){
        int l = o >> 5, q = o & 31;
        float v = xdbl[l*40 + DTR + q];
        size_t g = ((size_t)(b*Lseq + l0 + l))*DSTATE;
        if (q < DSTATE) Bm[g + q] = v;
        else            Cm[g + (q - DSTATE)] = v;
    }
}

// ---------------- Kernel C: pass 2, hierarchical chunk combine (layout-agnostic in r) --------------------
__global__ __launch_bounds__(256) void k_scan2(const float2* __restrict__ PSw,
        float* __restrict__ Iw){
    __shared__ float2 gps[16][16];
    __shared__ float  ge [16][16];
    int blk = blockIdx.x;               // 512 = b x 256 r-groups of 16
    int b  = blk >> 8;
    int r0 = (blk & 255) * 16;
    int t  = threadIdx.x;
    int rr = t & 15;                    // r within group
    int cg = t >> 4;                    // chunk-group 0..15 (16 chunks each)
    size_t base = ((size_t)(b*NC + cg*16))*4096 + r0 + rr;
    float Pl[16], Sl[16];
    float Pa = 1.f, Sa = 0.f;
    #pragma unroll
    for (int i=0;i<16;++i){
        float2 ps = PSw[base + (size_t)i*4096];
        Pl[i] = ps.x; Sl[i] = ps.y;
        Pa = ps.x * Pa;
        Sa = fmaf(ps.x, Sa, ps.y);
    }
    gps[cg][rr] = make_float2(Pa, Sa);
    __syncthreads();
    if (t < 16){
        float H = 0.f;
        #pragma unroll
        for (int g=0; g<16; ++g){
            float2 ps = gps[g][t];
            ge[g][t] = H;
            H = fmaf(ps.x, H, ps.y);
        }
    }
    __syncthreads();
    float H = ge[cg][rr];
    #pragma unroll
    for (int i=0;i<16;++i){
        Iw[base + (size_t)i*4096] = H;
        H = fmaf(Pl[i], H, Sl[i]);
    }
}

// ---------------- Kernel D: fused scan pass 3 + out_proj + LayerNorm + NCHW store -----------------------
// Round-2/8 structure; only the entry-state load adapts to the [s][d] Iw layout (16 coalesced b32 loads).
__global__ __launch_bounds__(256) void k_scan3out(const float* __restrict__ dt,
        const float* __restrict__ xc, const float* __restrict__ zs,
        const float* __restrict__ Bm, const float* __restrict__ Cm,
        const float* __restrict__ Alog, const float* __restrict__ Dv,
        const float* __restrict__ Iw,
        const float* __restrict__ Wout, const float* __restrict__ lng,
        const float* __restrict__ lnb, float* __restrict__ out){
    __shared__ float ysm[256*18];      // [d][l] stride 18
    __shared__ float os[128*18];       // [c][l] stride 18
    __shared__ float Bs[LC*DSTATE];    // 256
    __shared__ float Cs[LC*DSTATE];
    int blk = blockIdx.x;
    int b = blk >> 8, c = blk & 255;
    int l0 = c * LC;
    int t = threadIdx.x;               // = d in scan phase
    size_t gb = (size_t)(b*Lseq + l0);
    Bs[t] = Bm[gb*DSTATE + t];
    Cs[t] = Cm[gb*DSTATE + t];
    float Av[16];
    {
        const float4* Ap = (const float4*)(Alog + t*DSTATE);
        #pragma unroll
        for (int q=0;q<4;++q){
            float4 a = Ap[q];
            Av[q*4]   = -__expf(a.x);
            Av[q*4+1] = -__expf(a.y);
            Av[q*4+2] = -__expf(a.z);
            Av[q*4+3] = -__expf(a.w);
        }
    }
    bool fastA = true;
    #pragma unroll
    for (int i=1;i<16;++i)
        fastA = fastA && (fabsf(Av[i] - (float)(i+1)*Av[0]) <= 1e-6f*fabsf(Av[i]));
    float h[16];
    {   // Iw per-chunk layout [s][d]: h[s] = Iw[chunk_base + s*256 + t] (coalesced per s)
        const float* Ip = Iw + ((size_t)(b*NC + c))*4096 + t;
        #pragma unroll
        for (int s=0;s<16;++s) h[s] = Ip[s*256];
    }
    float Dd = Dv[t];
    // register-stage all 48 loads (independent -> single latency window)
    float dtv[LC], xcv[LC], zvv[LC];
    {
        const float* dtp = dt + gb*DIN + t;
        const float* xcp = xc + gb*DIN + t;
        const float* zsp = zs + gb*DIN + t;
        #pragma unroll
        for (int l=0;l<LC;++l){
            dtv[l] = dtp[l*DIN];
            xcv[l] = xcp[l*DIN];
            zvv[l] = zsp[l*DIN];
        }
    }
    __syncthreads();
    #pragma unroll
    for (int l=0;l<LC;++l){
        float dtl = dtv[l];
        float dx  = dtl*xcv[l];
        const float4* Bv = (const float4*)&Bs[l*DSTATE];
        const float4* Cv = (const float4*)&Cs[l*DSTATE];
        float4 B0 = Bv[0], B1 = Bv[1], B2 = Bv[2], B3 = Bv[3];
        float4 C0 = Cv[0], C1 = Cv[1], C2 = Cv[2], C3 = Cv[3];
        float dAv[16];
        if (fastA){
            build_dA(__expf(dtl*Av[0]), dAv);
        } else {
            #pragma unroll
            for (int i=0;i<16;++i) dAv[i] = __expf(dtl*Av[i]);
        }
        float y = 0.f;
        #define ST3(i, bval, cval) { h[i] = fmaf(dAv[i], h[i], dx*(bval)); y = fmaf(h[i], (cval), y); }
        ST3(0,B0.x,C0.x) ST3(1,B0.y,C0.y) ST3(2,B0.z,C0.z) ST3(3,B0.w,C0.w)
        ST3(4,B1.x,C1.x) ST3(5,B1.y,C1.y) ST3(6,B1.z,C1.z) ST3(7,B1.w,C1.w)
        ST3(8,B2.x,C2.x) ST3(9,B2.y,C2.y) ST3(10,B2.z,C2.z) ST3(11,B2.w,C2.w)
        ST3(12,B3.x,C3.x) ST3(13,B3.y,C3.y) ST3(14,B3.z,C3.z) ST3(15,B3.w,C3.w)
        #undef ST3
        ysm[t*18 + l] = (y + Dd*xcv[l])*zvv[l];
    }
    __syncthreads();
    // ---- out_proj: 16l x 128c tile. lg=t>>5 -> l {lg*2, lg*2+1}; cg=t&31 -> 4 c.
    int lg = t >> 5, cg = t & 31;
    int l0t = lg*2, c0 = cg*4;
    float acc[2][4];
    #pragma unroll
    for (int i=0;i<2;++i)
        #pragma unroll
        for (int j=0;j<4;++j) acc[i][j]=0.f;
    #pragma unroll 4
    for (int k=0;k<DIN;++k){
        float2 yv = *(const float2*)&ysm[k*18 + l0t];
        float4 wv = *(const float4*)&Wout[k*OUTC + c0];
        acc[0][0]=fmaf(yv.x,wv.x,acc[0][0]); acc[0][1]=fmaf(yv.x,wv.y,acc[0][1]);
        acc[0][2]=fmaf(yv.x,wv.z,acc[0][2]); acc[0][3]=fmaf(yv.x,wv.w,acc[0][3]);
        acc[1][0]=fmaf(yv.y,wv.x,acc[1][0]); acc[1][1]=fmaf(yv.y,wv.y,acc[1][1]);
        acc[1][2]=fmaf(yv.y,wv.z,acc[1][2]); acc[1][3]=fmaf(yv.y,wv.w,acc[1][3]);
    }
    // LayerNorm over c: reduce across the 32 lanes sharing this l (xor<=16 stays in half-wave)
    float4 gm = *(const float4*)&lng[c0];
    float4 bt = *(const float4*)&lnb[c0];
    #pragma unroll
    for (int i=0;i<2;++i){
        float rs = acc[i][0]+acc[i][1]+acc[i][2]+acc[i][3];
        #pragma unroll
        for (int m=16;m>0;m>>=1) rs += __shfl_xor(rs, m, 64);
        float mu = rs * (1.f/128.f);
        float d0 = acc[i][0]-mu, d1 = acc[i][1]-mu, d2 = acc[i][2]-mu, d3 = acc[i][3]-mu;
        float sq = d0*d0+d1*d1+d2*d2+d3*d3;
        #pragma unroll
        for (int m=16;m>0;m>>=1) sq += __shfl_xor(sq, m, 64);
        float rstd = rsqrtf(sq * (1.f/128.f) + 1e-5f);
        int lidx = l0t + i;
        os[(c0+0)*18 + lidx] = d0*rstd*gm.x + bt.x;
        os[(c0+1)*18 + lidx] = d1*rstd*gm.y + bt.y;
        os[(c0+2)*18 + lidx] = d2*rstd*gm.z + bt.z;
        os[(c0+3)*18 + lidx] = d3*rstd*gm.w + bt.w;
    }
    __syncthreads();
    // store: cc = t>>1 (0..127), sel = t&1 -> 8 consecutive l = 32B per lane; full 64B lines per c
    {
        int cc = t >> 1, sel = t & 1;
        const float* ip = &os[cc*18 + sel*8];
        float2 a0 = *(const float2*)(ip);
        float2 a1 = *(const float2*)(ip+2);
        float2 a2 = *(const float2*)(ip+4);
        float2 a3 = *(const float2*)(ip+6);
        float* op = out + ((size_t)(b*OUTC + cc))*Lseq + l0 + sel*8;
        *(float4*)(op)   = make_float4(a0.x,a0.y,a1.x,a1.y);
        *(float4*)(op+4) = make_float4(a2.x,a2.y,a3.x,a3.y);
    }
}

extern "C" void kernel_launch(void* const* d_in, const int* in_sizes, int n_in,
                              void* d_out, int out_size, void* d_ws, size_t ws_size,
                              hipStream_t stream) {
    const float* x1    = (const float*)d_in[0];
    const float* Win   = (const float*)d_in[1];
    const float* convw = (const float*)d_in[2];
    const float* convb = (const float*)d_in[3];
    const float* Wx    = (const float*)d_in[4];
    const float* Wdt   = (const float*)d_in[5];
    const float* bdt   = (const float*)d_in[6];
    const float* Alog  = (const float*)d_in[7];
    const float* Dv    = (const float*)d_in[8];
    const float* Wout  = (const float*)d_in[9];
    const float* lng   = (const float*)d_in[10];
    const float* lnb   = (const float*)d_in[11];
    float* out = (float*)d_out;

    float* ws  = (float*)d_ws;
    float* Iw  = ws;                        // 2,097,152 floats (entry states, written by scan2)
    float* zs  = Iw  + 2097152;             // 2,097,152
    float* xc  = zs  + 2097152;             // 2,097,152
    float* dt  = xc  + 2097152;             // 2,097,152
    float* Bm  = dt  + 2097152;             //   131,072
    float* Cm  = Bm  + 131072;              //   131,072
    float2* PSw = (float2*)(Cm + 131072);   // 2,097,152 float2 (~51.4 MB total)

    k_inconv_scan1<<<512, 256, 0, stream>>>(x1, Win, convw, convb, Wx, Wdt, bdt, Alog,
                                            zs, xc, dt, Bm, Cm, PSw);
    k_scan2       <<<512, 256, 0, stream>>>(PSw, Iw);
    k_scan3out    <<<512, 256, 0, stream>>>(dt, xc, zs, Bm, Cm, Alog, Dv, Iw,
                                            Wout, lng, lnb, out);
}